// Round 6
// baseline (205.767 us; speedup 1.0000x reference)
//
#include <hip/hip_runtime.h>

typedef __bf16 bf16x8 __attribute__((ext_vector_type(8)));
typedef float  f32x4  __attribute__((ext_vector_type(4)));

#define N_SITES 400000
#define KVOL    27
#define NPAD    (N_SITES + 16)
#define ZROW    N_SITES                  // all-zero row for invalid neighbors

#define FB_BYTES  ((size_t)NPAD * 128)
#define WSB_BYTES ((size_t)KVOL * 8 * 64 * 16)
#define WS_NEED   (FB_BYTES + WSB_BYTES)

// ---------- weight repack: fp32 [27][64][64] -> bf16 MFMA B-fragments ----------
// Fragment (ko, ks, cb), position (lane, e) holds kernel[ko][ci][co],
// ci = ks*32 + (lane>>4)*8 + e, co = cb*16 + (lane&15).
__global__ __launch_bounds__(256) void conv_prep(const float* __restrict__ kern,
                                                 bf16x8* __restrict__ wsb) {
    int tid = blockIdx.x * 256 + threadIdx.x;
    if (tid >= KVOL * 2 * 4 * 64) return;
    int lane = tid & 63;
    int cb   = (tid >> 6) & 3;
    int ks   = (tid >> 8) & 1;
    int ko   = tid >> 9;
    int i = lane & 15, g = lane >> 4;
    int co = cb * 16 + i;
    bf16x8 v;
#pragma unroll
    for (int e = 0; e < 8; ++e) {
        int ci = ks * 32 + g * 8 + e;
        v[e] = (__bf16)kern[(ko * 64 + ci) * 64 + co];
    }
    wsb[tid] = v;
}

// ---------- feats fp32 -> bf16 (plus zero pad rows) ----------
__global__ __launch_bounds__(256) void prep_feats(const float* __restrict__ f,
                                                  bf16x8* __restrict__ dst) {
    int tid = blockIdx.x * 256 + threadIdx.x;
    if (tid >= NPAD * 64 / 8) return;
    bf16x8 v;
    if (tid < N_SITES * 64 / 8) {
        const f32x4* s = (const f32x4*)(f + (size_t)tid * 8);
        f32x4 a = s[0], b = s[1];
#pragma unroll
        for (int e = 0; e < 4; ++e) { v[e] = (__bf16)a[e]; v[e + 4] = (__bf16)b[e]; }
    } else {
#pragma unroll
        for (int e = 0; e < 8; ++e) v[e] = (__bf16)0.0f;
    }
    dst[tid] = v;
}

// ---------- async global->LDS stage of one offset's B fragments (8 KB) ----------
__device__ __forceinline__ void stage_b(const bf16x8* __restrict__ wsb, int k,
                                        char* buf) {
    const char* g = (const char*)(wsb + (size_t)k * 8 * 64);
    int wave = threadIdx.x >> 6;
    int t    = threadIdx.x;
    __builtin_amdgcn_global_load_lds(
        (const __attribute__((address_space(1))) char*)(g + (size_t)t * 16),
        (__attribute__((address_space(3))) char*)(buf + wave * 1024), 16, 0, 0);
    __builtin_amdgcn_global_load_lds(
        (const __attribute__((address_space(1))) char*)(g + 4096 + (size_t)t * 16),
        (__attribute__((address_space(3))) char*)(buf + 4096 + wave * 1024), 16, 0, 0);
}

// ---------- A state: 64 rows (4 row-tiles) x K=64 (2 halves) ----------
struct Idx4 { int a, b, c, d; };
struct ASet { bf16x8 f0l, f0h, f1l, f1h, f2l, f2h, f3l, f3h; };

__device__ __forceinline__ void gather64(const bf16x8* __restrict__ fb, int g,
                                         const Idx4& I, ASet& s) {
    // sanitize: OOB / -1 -> ZROW (covers tail-block garbage rows too)
    unsigned r0 = ((unsigned)I.a < (unsigned)N_SITES) ? (unsigned)I.a : (unsigned)ZROW;
    unsigned r1 = ((unsigned)I.b < (unsigned)N_SITES) ? (unsigned)I.b : (unsigned)ZROW;
    unsigned r2 = ((unsigned)I.c < (unsigned)N_SITES) ? (unsigned)I.c : (unsigned)ZROW;
    unsigned r3 = ((unsigned)I.d < (unsigned)N_SITES) ? (unsigned)I.d : (unsigned)ZROW;
    const bf16x8* p0 = fb + (((size_t)r0) << 3) + g;
    s.f0l = p0[0];  s.f0h = p0[4];
    const bf16x8* p1 = fb + (((size_t)r1) << 3) + g;
    s.f1l = p1[0];  s.f1h = p1[4];
    const bf16x8* p2 = fb + (((size_t)r2) << 3) + g;
    s.f2l = p2[0];  s.f2h = p2[4];
    const bf16x8* p3 = fb + (((size_t)r3) << 3) + g;
    s.f3l = p3[0];  s.f3h = p3[4];
}

__device__ __forceinline__ void mfma32(const char* bbuf, int lane,
                                       const ASet& s, f32x4 acc[4][4]) {
    const bf16x8* B = (const bf16x8*)bbuf;
#pragma unroll
    for (int cb = 0; cb < 4; ++cb) {
        bf16x8 b0 = B[cb * 64 + lane];
        bf16x8 b1 = B[(4 + cb) * 64 + lane];
        acc[0][cb] = __builtin_amdgcn_mfma_f32_16x16x32_bf16(s.f0l, b0, acc[0][cb], 0, 0, 0);
        acc[0][cb] = __builtin_amdgcn_mfma_f32_16x16x32_bf16(s.f0h, b1, acc[0][cb], 0, 0, 0);
        acc[1][cb] = __builtin_amdgcn_mfma_f32_16x16x32_bf16(s.f1l, b0, acc[1][cb], 0, 0, 0);
        acc[1][cb] = __builtin_amdgcn_mfma_f32_16x16x32_bf16(s.f1h, b1, acc[1][cb], 0, 0, 0);
        acc[2][cb] = __builtin_amdgcn_mfma_f32_16x16x32_bf16(s.f2l, b0, acc[2][cb], 0, 0, 0);
        acc[2][cb] = __builtin_amdgcn_mfma_f32_16x16x32_bf16(s.f2h, b1, acc[2][cb], 0, 0, 0);
        acc[3][cb] = __builtin_amdgcn_mfma_f32_16x16x32_bf16(s.f3l, b0, acc[3][cb], 0, 0, 0);
        acc[3][cb] = __builtin_amdgcn_mfma_f32_16x16x32_bf16(s.f3h, b1, acc[3][cb], 0, 0, 0);
    }
}

// ---------- steady body, iter k in [0,26) ----------
// vmem order per iter: stage B(k+1) [2] then gather A(k+1) [8].
// End barrier waits vmcnt(8): drains stage(k+1), keeps gather(k+1) in flight.
__device__ __forceinline__ void body(int k,
    const bf16x8* __restrict__ fb, const bf16x8* __restrict__ wsb,
    char (*ldsb)[8192], const int* ldsi, int lane, int wave, int g,
    const ASet& Su, ASet& Sl, const Idx4& Iu, Idx4& Il, f32x4 acc[4][4])
{
    __builtin_amdgcn_sched_barrier(0);
    stage_b(wsb, k + 1, ldsb[(k + 1) & 1]);      // 2 vmem
    __builtin_amdgcn_sched_barrier(0);
    gather64(fb, g, Iu, Sl);                     // 8 vmem: A(k+1)
    int kidx = (k + 2 > KVOL - 1) ? (KVOL - 1) : (k + 2);
    const int* ip = ldsi + kidx * 256 + wave * 64 + (lane & 15);
    Il.a = ip[0];  Il.b = ip[16];  Il.c = ip[32];  Il.d = ip[48];   // idx(k+2)
    __builtin_amdgcn_sched_barrier(0);
    __builtin_amdgcn_s_setprio(1);
    mfma32(ldsb[k & 1], lane, Su, acc);          // 8 ds_read_b128 + 32 MFMA
    __builtin_amdgcn_s_setprio(0);
    __builtin_amdgcn_sched_barrier(0);
    asm volatile("s_waitcnt vmcnt(8)" ::: "memory");
    __builtin_amdgcn_sched_barrier(0);
    __builtin_amdgcn_s_barrier();
}

__global__ __launch_bounds__(256, 3) void conv_main6(
    const bf16x8* __restrict__ featsb,
    const int*   __restrict__ nmap,
    const float* __restrict__ bias,
    const bf16x8* __restrict__ wsb,
    float* __restrict__ out)
{
    __shared__ __align__(1024) char ldsb[2][8192];      // double-buffered B
    __shared__ __align__(16)   int  ldsi[KVOL * 256];   // block's nmap slab (27.6 KB)

    const int lane = threadIdx.x & 63;
    const int wave = threadIdx.x >> 6;
    const int i = lane & 15;
    const int g = lane >> 4;
    const int brow = blockIdx.x * 256;
    const int row0 = brow + wave * 64;

    // ---- prologue: stage nmap slab: 27 offsets x 256 rows = 1728 x 16B chunks ----
    {
#pragma unroll
        for (int r = 0; r < 7; ++r) {
            int c = r * 256 + threadIdx.x;
            if (c < KVOL * 64) {                 // wave-uniform branch (r=6: wave 3 skips)
                int k = c >> 6, j = c & 63;
                int srcrow = brow + j * 4;
                if (srcrow > N_SITES - 4) srcrow = N_SITES - 4;   // tail clamp
                __builtin_amdgcn_global_load_lds(
                    (const __attribute__((address_space(1))) char*)
                        ((const char*)(nmap + (size_t)k * N_SITES + srcrow)),
                    (__attribute__((address_space(3))) char*)
                        ((char*)ldsi + (r * 256 + wave * 64) * 16),
                    16, 0, 0);
            }
        }
    }
    stage_b(wsb, 0, ldsb[0]);

    float bv[4];
#pragma unroll
    for (int cb = 0; cb < 4; ++cb) bv[cb] = bias[cb * 16 + i];

    __syncthreads();   // full drain once: slab + B(0) ready

    f32x4 acc[4][4] = {};
    ASet S0, S1;
    Idx4 IA, IB, I0;

    {
        const int* ip0 = ldsi + 0 * 256 + wave * 64 + i;
        I0.a = ip0[0];  I0.b = ip0[16];  I0.c = ip0[32];  I0.d = ip0[48];
        const int* ip1 = ldsi + 1 * 256 + wave * 64 + i;
        IA.a = ip1[0];  IA.b = ip1[16];  IA.c = ip1[32];  IA.d = ip1[48];
    }
    gather64(featsb, g, I0, S0);   // A(0)
    IB = I0;                       // dead init (overwritten in body(0))

    // even k: use S0/buf[k&1], load S1 via IA(idx k+1), fetch IB(idx k+2); odd: swapped
#pragma unroll 1
    for (int j = 0; j < 13; ++j) {
        int k = 2 * j;
        body(k,     featsb, wsb, ldsb, ldsi, lane, wave, g, S0, S1, IA, IB, acc);
        body(k + 1, featsb, wsb, ldsb, ldsi, lane, wave, g, S1, S0, IB, IA, acc);
    }
    // tail k=26: B(26) staged at k=25 into ldsb[0]; A(26) gathered at k=25 into S0
    __builtin_amdgcn_s_setprio(1);
    mfma32(ldsb[0], lane, S0, acc);
    __builtin_amdgcn_s_setprio(0);

    // ---- epilogue: C/D layout col = lane&15, row = (lane>>4)*4 + reg ----
    if (row0 < N_SITES) {          // wave-uniform tail guard (tiles are 16-aligned)
#pragma unroll
        for (int t = 0; t < 4; ++t)
#pragma unroll
            for (int cb = 0; cb < 4; ++cb)
#pragma unroll
                for (int r = 0; r < 4; ++r)
                    __builtin_nontemporal_store(acc[t][cb][r] + bv[cb],
                        &out[(size_t)(row0 + t * 16 + g * 4 + r) * 64 + cb * 16 + i]);
    }
}

// ---------- fallback (only if ws too small): round-1 kernel ----------
__global__ __launch_bounds__(256) void conv_main1(
    const float* __restrict__ feats,
    const int*   __restrict__ nmap,
    const float* __restrict__ bias,
    const bf16x8* __restrict__ wsb,
    float* __restrict__ out)
{
    const int lane = threadIdx.x & 63;
    const int wave = threadIdx.x >> 6;
    const int i = lane & 15;
    const int g = lane >> 4;
    const int row0 = (blockIdx.x * 4 + wave) * 32;

    f32x4 acc[2][4] = {};
    for (int k = 0; k < KVOL; ++k) {
        bf16x8 bfr[2][4];
#pragma unroll
        for (int ks = 0; ks < 2; ++ks)
#pragma unroll
            for (int cb = 0; cb < 4; ++cb)
                bfr[ks][cb] = wsb[(k * 8 + ks * 4 + cb) * 64 + lane];
#pragma unroll
        for (int t = 0; t < 2; ++t) {
            const int row = row0 + t * 16 + i;
            const int idx = nmap[k * N_SITES + row];
            const int src = idx < 0 ? 0 : idx;
            const f32x4* fp = (const f32x4*)(feats + (size_t)src * 64 + g * 8);
            f32x4 v0 = fp[0], v1 = fp[1], v2 = fp[8], v3 = fp[9];
            union { bf16x8 v; unsigned u[4]; } A0, A1;
#pragma unroll
            for (int e = 0; e < 4; ++e) {
                A0.v[e] = (__bf16)v0[e]; A0.v[e + 4] = (__bf16)v1[e];
                A1.v[e] = (__bf16)v2[e]; A1.v[e + 4] = (__bf16)v3[e];
            }
#pragma unroll
            for (int e = 0; e < 4; ++e) {
                A0.u[e] = (idx < 0) ? 0u : A0.u[e];
                A1.u[e] = (idx < 0) ? 0u : A1.u[e];
            }
#pragma unroll
            for (int cb = 0; cb < 4; ++cb)
                acc[t][cb] = __builtin_amdgcn_mfma_f32_16x16x32_bf16(A0.v, bfr[0][cb], acc[t][cb], 0, 0, 0);
#pragma unroll
            for (int cb = 0; cb < 4; ++cb)
                acc[t][cb] = __builtin_amdgcn_mfma_f32_16x16x32_bf16(A1.v, bfr[1][cb], acc[t][cb], 0, 0, 0);
        }
    }
    float bv[4];
#pragma unroll
    for (int cb = 0; cb < 4; ++cb) bv[cb] = bias[cb * 16 + i];
#pragma unroll
    for (int t = 0; t < 2; ++t)
#pragma unroll
        for (int cb = 0; cb < 4; ++cb)
#pragma unroll
            for (int r = 0; r < 4; ++r)
                out[(size_t)(row0 + t * 16 + g * 4 + r) * 64 + cb * 16 + i] =
                    acc[t][cb][r] + bv[cb];
}

extern "C" void kernel_launch(void* const* d_in, const int* in_sizes, int n_in,
                              void* d_out, int out_size, void* d_ws, size_t ws_size,
                              hipStream_t stream) {
    const float* feats = (const float*)d_in[0];
    const float* kern  = (const float*)d_in[1];
    const float* bias  = (const float*)d_in[2];
    const int*   nmap  = (const int*)d_in[3];
    float* out = (float*)d_out;

    if (ws_size >= WS_NEED) {
        bf16x8* fb  = (bf16x8*)d_ws;
        bf16x8* wsb = (bf16x8*)((char*)d_ws + FB_BYTES);
        prep_feats<<<(NPAD * 64 / 8 + 255) / 256, 256, 0, stream>>>(feats, fb);
        conv_prep<<<(KVOL * 2 * 4 * 64 + 255) / 256, 256, 0, stream>>>(kern, wsb);
        // 64 rows/wave, 4 waves/block -> 256 rows/block; ceil(400000/256) = 1563
        conv_main6<<<1563, 256, 0, stream>>>(fb, nmap, bias, wsb, out);
    } else {
        bf16x8* wsb = (bf16x8*)d_ws;
        conv_prep<<<(KVOL * 2 * 4 * 64 + 255) / 256, 256, 0, stream>>>(kern, wsb);
        conv_main1<<<3125, 256, 0, stream>>>(feats, nmap, bias, wsb, out);
    }
}

// Round 7
// 194.240 us; speedup vs baseline: 1.0593x; 1.0593x over previous
//
#include <hip/hip_runtime.h>

typedef __bf16 bf16x8 __attribute__((ext_vector_type(8)));
typedef float  f32x4  __attribute__((ext_vector_type(4)));

#define N_SITES 400000
#define KVOL    27
#define NPAD    (N_SITES + 16)
#define ZROW    N_SITES                  // all-zero row for invalid neighbors

#define FB_BYTES  ((size_t)NPAD * 128)
#define WSB_BYTES ((size_t)KVOL * 8 * 64 * 16)
#define WS_NEED   (FB_BYTES + WSB_BYTES)

// ---------- weight repack: fp32 [27][64][64] -> bf16 MFMA B-fragments ----------
// Fragment (ko, ks, cb), position (lane, e) holds kernel[ko][ci][co],
// ci = ks*32 + (lane>>4)*8 + e, co = cb*16 + (lane&15).
__global__ __launch_bounds__(256) void conv_prep(const float* __restrict__ kern,
                                                 bf16x8* __restrict__ wsb) {
    int tid = blockIdx.x * 256 + threadIdx.x;
    if (tid >= KVOL * 2 * 4 * 64) return;
    int lane = tid & 63;
    int cb   = (tid >> 6) & 3;
    int ks   = (tid >> 8) & 1;
    int ko   = tid >> 9;
    int i = lane & 15, g = lane >> 4;
    int co = cb * 16 + i;
    bf16x8 v;
#pragma unroll
    for (int e = 0; e < 8; ++e) {
        int ci = ks * 32 + g * 8 + e;
        v[e] = (__bf16)kern[(ko * 64 + ci) * 64 + co];
    }
    wsb[tid] = v;
}

// ---------- feats fp32 -> bf16 (plus zero pad rows) ----------
__global__ __launch_bounds__(256) void prep_feats(const float* __restrict__ f,
                                                  bf16x8* __restrict__ dst) {
    int tid = blockIdx.x * 256 + threadIdx.x;
    if (tid >= NPAD * 64 / 8) return;
    bf16x8 v;
    if (tid < N_SITES * 64 / 8) {
        const f32x4* s = (const f32x4*)(f + (size_t)tid * 8);
        f32x4 a = s[0], b = s[1];
#pragma unroll
        for (int e = 0; e < 4; ++e) { v[e] = (__bf16)a[e]; v[e + 4] = (__bf16)b[e]; }
    } else {
#pragma unroll
        for (int e = 0; e < 8; ++e) v[e] = (__bf16)0.0f;
    }
    dst[tid] = v;
}

// ---------- async global->LDS stage of one offset's B fragments (8 KB) ----------
__device__ __forceinline__ void stage_b(const bf16x8* __restrict__ wsb, int k,
                                        char* buf) {
    const char* g = (const char*)(wsb + (size_t)k * 8 * 64);
    int wave = threadIdx.x >> 6;
    int t    = threadIdx.x;
    __builtin_amdgcn_global_load_lds(
        (const __attribute__((address_space(1))) char*)(g + (size_t)t * 16),
        (__attribute__((address_space(3))) char*)(buf + wave * 1024), 16, 0, 0);
    __builtin_amdgcn_global_load_lds(
        (const __attribute__((address_space(1))) char*)(g + 4096 + (size_t)t * 16),
        (__attribute__((address_space(3))) char*)(buf + 4096 + wave * 1024), 16, 0, 0);
}

// ---------- gather 64 feats rows into wave-private LDS, 8 rows/instr ----------
// Instr j: lane l = 8p+c reads global row idx[8j+p], chunk (c ^ (p&7))  (source-
// side XOR swizzle), lands at LDS byte (8j+p)*128 + c*16 (linear lane*16 dest).
// So LDS[r][c] holds global chunk c^(r&7); reads apply the same XOR -> 2-way banks.
__device__ __forceinline__ void gather_lds(const char* __restrict__ fbase, int Iv,
                                           int permbase, int coff, char* abuf) {
#pragma unroll
    for (int j = 0; j < 8; ++j) {
        int idx = __builtin_amdgcn_ds_bpermute(permbase + j * 32, Iv);
        unsigned r = ((unsigned)idx < (unsigned)N_SITES) ? (unsigned)idx
                                                         : (unsigned)ZROW;
        const char* p = fbase + (((size_t)r) << 7) + coff;
        __builtin_amdgcn_global_load_lds(
            (const __attribute__((address_space(1))) char*)p,
            (__attribute__((address_space(3))) char*)(abuf + j * 1024), 16, 0, 0);
    }
}

// ---------- 16 ds_read_b128 + 32 MFMA: A (swizzled) and B from LDS ----------
__device__ __forceinline__ void mfma32_lds(const char* abuf, const char* bbuf,
                                           int lane, f32x4 acc[4][4]) {
    const int i = lane & 15, g = lane >> 4;
    const int sw = i & 7;
    const int c0 = ((g ^ sw)) << 4;          // chunk g  (k = 8g..8g+7)
    const int c1 = (((4 + g) ^ sw)) << 4;    // chunk 4+g (k = 32+8g..)
    bf16x8 A0[4], A1[4], B0[4], B1[4];
#pragma unroll
    for (int t = 0; t < 4; ++t) {
        const char* rowp = abuf + (t * 16 + i) * 128;
        A0[t] = *(const bf16x8*)(rowp + c0);
        A1[t] = *(const bf16x8*)(rowp + c1);
    }
    const bf16x8* B = (const bf16x8*)bbuf;
#pragma unroll
    for (int cb = 0; cb < 4; ++cb) {
        B0[cb] = B[cb * 64 + lane];
        B1[cb] = B[(4 + cb) * 64 + lane];
    }
#pragma unroll
    for (int cb = 0; cb < 4; ++cb)
#pragma unroll
        for (int t = 0; t < 4; ++t) {
            acc[t][cb] = __builtin_amdgcn_mfma_f32_16x16x32_bf16(A0[t], B0[cb], acc[t][cb], 0, 0, 0);
            acc[t][cb] = __builtin_amdgcn_mfma_f32_16x16x32_bf16(A1[t], B1[cb], acc[t][cb], 0, 0, 0);
        }
}

// ---------- steady body, k in [0,26) ----------
// vmem issue order: stage B(k+1) [2] ; Iv(k+2) [1] ; gather-LDS A(k+1) [8].
// vmcnt(11) before MFMA: retires gather A(k) (8 issued last iter).
// vmcnt(8)+s_barrier at end: retires stage+Iv, leaves gather A(k+1) in flight.
__device__ __forceinline__ void body(int k, const char* __restrict__ fbase,
    const bf16x8* __restrict__ wsb, char (*ldsb)[8192], char* abase,
    const int* __restrict__ nrow, int permbase, int coff, int lane,
    int IvUse, int& IvLoad, f32x4 acc[4][4])
{
    __builtin_amdgcn_sched_barrier(0);
    stage_b(wsb, k + 1, ldsb[(k + 1) & 1]);                       // 2 vmem
    __builtin_amdgcn_sched_barrier(0);
    int kk2 = (k + 2 > KVOL - 1) ? (KVOL - 1) : (k + 2);
    IvLoad = __builtin_nontemporal_load(nrow + (size_t)kk2 * N_SITES);  // 1 vmem
    __builtin_amdgcn_sched_barrier(0);
    gather_lds(fbase, IvUse, permbase, coff, abase + ((k + 1) & 1) * 8192); // 8 vmem
    __builtin_amdgcn_sched_barrier(0);
    asm volatile("s_waitcnt vmcnt(11)" ::: "memory");
    __builtin_amdgcn_sched_barrier(0);
    __builtin_amdgcn_s_setprio(1);
    mfma32_lds(abase + (k & 1) * 8192, ldsb[k & 1], lane, acc);
    __builtin_amdgcn_s_setprio(0);
    __builtin_amdgcn_sched_barrier(0);
    asm volatile("s_waitcnt vmcnt(8)" ::: "memory");
    __builtin_amdgcn_sched_barrier(0);
    __builtin_amdgcn_s_barrier();
}

__global__ __launch_bounds__(256, 2) void conv_main7(
    const char* __restrict__ fbase,      // bf16 feats, 128 B/row, +ZROW
    const int*  __restrict__ nmap,
    const float* __restrict__ bias,
    const bf16x8* __restrict__ wsb,
    float* __restrict__ out)
{
    __shared__ __align__(1024) char ldsb[2][8192];       // B double-buffer (shared)
    __shared__ __align__(1024) char ldsa[4][2][8192];    // A dbuf, wave-private

    const int lane = threadIdx.x & 63;
    const int wave = threadIdx.x >> 6;
    const int i = lane & 15, g = lane >> 4;
    const int brow = blockIdx.x * 256;
    const int row0 = brow + wave * 64;

    int rowme = row0 + lane;
    if (rowme > N_SITES - 1) rowme = N_SITES - 1;        // tail clamp (in-bounds)
    const int* nrow = nmap + rowme;
    const int permbase = (lane >> 3) << 2;               // bpermute byte index base
    const int coff = ((lane & 7) ^ (lane >> 3)) << 4;    // source-side XOR swizzle
    char* abase = (char*)ldsa + wave * 16384;

    float bv[4];
#pragma unroll
    for (int cb = 0; cb < 4; ++cb) bv[cb] = bias[cb * 16 + i];

    // ---- prologue: B(0), idx(0), idx(1), A(0) ----
    int Iv0 = nrow[0];
    int IvA = nrow[N_SITES];                             // idx(1)
    int IvB;
    stage_b(wsb, 0, ldsb[0]);
    gather_lds(fbase, Iv0, permbase, coff, abase);       // A(0) -> abuf[0]
    __syncthreads();                                     // full drain, once

    f32x4 acc[4][4] = {};

#pragma unroll 1
    for (int jj = 0; jj < 13; ++jj) {                    // k = 0..25
        body(2 * jj,     fbase, wsb, ldsb, abase, nrow, permbase, coff, lane, IvA, IvB, acc);
        body(2 * jj + 1, fbase, wsb, ldsb, abase, nrow, permbase, coff, lane, IvB, IvA, acc);
    }

    // ---- k = 26: A(26) in abuf[0] (gathered at k=25), B(26) in ldsb[0] ----
    asm volatile("s_waitcnt vmcnt(0)" ::: "memory");
    __builtin_amdgcn_sched_barrier(0);
    __builtin_amdgcn_s_setprio(1);
    mfma32_lds(abase, ldsb[0], lane, acc);
    __builtin_amdgcn_s_setprio(0);

    // ---- epilogue: C/D layout col = lane&15, row = (lane>>4)*4 + reg ----
    if (row0 < N_SITES) {                                // whole-wave guard
#pragma unroll
        for (int t = 0; t < 4; ++t)
#pragma unroll
            for (int cb = 0; cb < 4; ++cb)
#pragma unroll
                for (int r = 0; r < 4; ++r)
                    __builtin_nontemporal_store(acc[t][cb][r] + bv[cb],
                        &out[(size_t)(row0 + t * 16 + g * 4 + r) * 64 + cb * 16 + i]);
    }
}

// ---------- fallback (only if ws too small): round-1 kernel ----------
__global__ __launch_bounds__(256) void conv_main1(
    const float* __restrict__ feats,
    const int*   __restrict__ nmap,
    const float* __restrict__ bias,
    const bf16x8* __restrict__ wsb,
    float* __restrict__ out)
{
    const int lane = threadIdx.x & 63;
    const int wave = threadIdx.x >> 6;
    const int i = lane & 15;
    const int g = lane >> 4;
    const int row0 = (blockIdx.x * 4 + wave) * 32;

    f32x4 acc[2][4] = {};
    for (int k = 0; k < KVOL; ++k) {
        bf16x8 bfr[2][4];
#pragma unroll
        for (int ks = 0; ks < 2; ++ks)
#pragma unroll
            for (int cb = 0; cb < 4; ++cb)
                bfr[ks][cb] = wsb[(k * 8 + ks * 4 + cb) * 64 + lane];
#pragma unroll
        for (int t = 0; t < 2; ++t) {
            const int row = row0 + t * 16 + i;
            const int idx = nmap[k * N_SITES + row];
            const int src = idx < 0 ? 0 : idx;
            const f32x4* fp = (const f32x4*)(feats + (size_t)src * 64 + g * 8);
            f32x4 v0 = fp[0], v1 = fp[1], v2 = fp[8], v3 = fp[9];
            union { bf16x8 v; unsigned u[4]; } A0, A1;
#pragma unroll
            for (int e = 0; e < 4; ++e) {
                A0.v[e] = (__bf16)v0[e]; A0.v[e + 4] = (__bf16)v1[e];
                A1.v[e] = (__bf16)v2[e]; A1.v[e + 4] = (__bf16)v3[e];
            }
#pragma unroll
            for (int e = 0; e < 4; ++e) {
                A0.u[e] = (idx < 0) ? 0u : A0.u[e];
                A1.u[e] = (idx < 0) ? 0u : A1.u[e];
            }
#pragma unroll
            for (int cb = 0; cb < 4; ++cb)
                acc[t][cb] = __builtin_amdgcn_mfma_f32_16x16x32_bf16(A0.v, bfr[0][cb], acc[t][cb], 0, 0, 0);
#pragma unroll
            for (int cb = 0; cb < 4; ++cb)
                acc[t][cb] = __builtin_amdgcn_mfma_f32_16x16x32_bf16(A1.v, bfr[1][cb], acc[t][cb], 0, 0, 0);
        }
    }
    float bv[4];
#pragma unroll
    for (int cb = 0; cb < 4; ++cb) bv[cb] = bias[cb * 16 + i];
#pragma unroll
    for (int t = 0; t < 2; ++t)
#pragma unroll
        for (int cb = 0; cb < 4; ++cb)
#pragma unroll
            for (int r = 0; r < 4; ++r)
                out[(size_t)(row0 + t * 16 + g * 4 + r) * 64 + cb * 16 + i] =
                    acc[t][cb][r] + bv[cb];
}

extern "C" void kernel_launch(void* const* d_in, const int* in_sizes, int n_in,
                              void* d_out, int out_size, void* d_ws, size_t ws_size,
                              hipStream_t stream) {
    const float* feats = (const float*)d_in[0];
    const float* kern  = (const float*)d_in[1];
    const float* bias  = (const float*)d_in[2];
    const int*   nmap  = (const int*)d_in[3];
    float* out = (float*)d_out;

    if (ws_size >= WS_NEED) {
        bf16x8* fb  = (bf16x8*)d_ws;
        bf16x8* wsb = (bf16x8*)((char*)d_ws + FB_BYTES);
        prep_feats<<<(NPAD * 64 / 8 + 255) / 256, 256, 0, stream>>>(feats, fb);
        conv_prep<<<(KVOL * 2 * 4 * 64 + 255) / 256, 256, 0, stream>>>(kern, wsb);
        // 64 rows/wave, 4 waves/block -> 256 rows/block; ceil(400000/256) = 1563
        conv_main7<<<1563, 256, 0, stream>>>((const char*)fb, nmap, bias, wsb, out);
    } else {
        bf16x8* wsb = (bf16x8*)d_ws;
        conv_prep<<<(KVOL * 2 * 4 * 64 + 255) / 256, 256, 0, stream>>>(kern, wsb);
        conv_main1<<<3125, 256, 0, stream>>>(feats, nmap, bias, wsb, out);
    }
}